// Round 2
// baseline (1539.209 us; speedup 1.0000x reference)
//
#include <hip/hip_runtime.h>

#define NN 128   // points per set
#define NB 128   // batches
#define ND 5     // feature dim

__device__ __forceinline__ float wrap_phi(float x) {
  const float PI_F   = 3.14159265358979323846f;
  const float TWO_PI = 6.28318530717958647692f;
  float t = x + PI_F;
  float w = t - floorf(t * (1.0f / TWO_PI)) * TWO_PI;  // jnp.remainder semantics
  return w - PI_F;
}

// One block (64 threads = 1 wave) solves one batch's 128x128 assignment via
// Jonker-Volgenant (identical recurrence to the reference), then accumulates
// the 5 per-feature squared-error sums into global accumulators.
__global__ __launch_bounds__(64) void set2set_hungarian(
    const float* __restrict__ inp, const float* __restrict__ tgt,
    float* __restrict__ sums)
{
  const int b = blockIdx.x;
  const int lane = threadIdx.x;

  __shared__ __align__(16) float Csh[NN * NN]; // cost matrix, row-major, 64 KB
  __shared__ float u[NN + 1];                  // row duals, 1-indexed rows
  __shared__ float inpS[NN * ND];              // staged input rows
  __shared__ int   p[NN + 1];                  // p[j] = row matched to col j (1-idx), 0 = free
  __shared__ int   way[NN + 1];

  const float* inB = inp + (size_t)b * NN * ND;
  const float* tgB = tgt + (size_t)b * NN * ND;

  for (int idx = lane; idx < NN * ND; idx += 64) inpS[idx] = inB[idx];
  for (int idx = lane; idx <= NN; idx += 64) { u[idx] = 0.0f; p[idx] = 0; way[idx] = 0; }
  __syncthreads();

  // this lane owns 0-indexed columns jA, jB  (1-indexed c1A, c1B)
  const int jA = 2 * lane;
  const int jB = 2 * lane + 1;
  const int c1A = jA + 1, c1B = jB + 1;

  float tA[ND], tB[ND];
  #pragma unroll
  for (int d = 0; d < ND; ++d) { tA[d] = tgB[jA * ND + d]; tB[d] = tgB[jB * ND + d]; }

  // build cost matrix: C[i][j] = ||input_i - target_j||_2
  for (int i = 0; i < NN; ++i) {
    float sA = 0.f, sB = 0.f;
    #pragma unroll
    for (int d = 0; d < ND; ++d) {
      float x = inpS[i * ND + d];
      float da = x - tA[d]; sA = fmaf(da, da, sA);
      float db = x - tB[d]; sB = fmaf(db, db, sB);
    }
    ((float2*)(Csh + i * NN))[lane] = make_float2(sqrtf(sA), sqrtf(sB));
  }
  __syncthreads();

  const float INFV = 3.4028235e38f;
  float vA = 0.f, vB = 0.f;   // column duals, register-resident per lane

  for (int i = 1; i <= NN; ++i) {
    float mA = INFV, mB = INFV;
    bool usedA = false, usedB = false;
    int j0 = 0;
    for (int guard = 0; guard <= NN + 1; ++guard) {
      // mark j0 used (column 0 is implicitly always used; p[0] == i)
      usedA |= (j0 == c1A);
      usedB |= (j0 == c1B);
      int   i0  = (j0 == 0) ? i : p[j0];     // broadcast LDS read (uniform)
      float ui0 = u[i0];                     // broadcast LDS read (uniform)
      float2 c = ((const float2*)(Csh + (size_t)(i0 - 1) * NN))[lane];
      if (!usedA) { float cur = c.x - ui0 - vA; if (cur < mA) { mA = cur; way[c1A] = j0; } }
      if (!usedB) { float cur = c.y - ui0 - vB; if (cur < mB) { mB = cur; way[c1B] = j0; } }

      // delta = min over unused columns of minv  (exact fp32 min)
      float lmin = fminf(usedA ? INFV : mA, usedB ? INFV : mB);
      #pragma unroll
      for (int off = 32; off > 0; off >>= 1)
        lmin = fminf(lmin, __shfl_xor(lmin, off));
      float delta = lmin;

      // argmin column with lowest-index tie-break (matches np.argmin)
      unsigned long long mskA = __ballot(!usedA && (mA == delta));
      unsigned long long mskB = __ballot(!usedB && (mB == delta));
      int cAi = mskA ? (2 * (__ffsll(mskA) - 1) + 1) : (2 * NN + 9);
      int cBi = mskB ? (2 * (__ffsll(mskB) - 1) + 2) : (2 * NN + 9);
      int j1 = min(cAi, cBi);

      // dual updates (distinct scatter addresses: matched rows are unique)
      if (usedA) { vA -= delta; u[p[c1A]] += delta; } else { mA -= delta; }
      if (usedB) { vB -= delta; u[p[c1B]] += delta; } else { mB -= delta; }
      if (lane == 0) u[i] += delta;          // column 0 carries p[0] = i

      j0 = j1;
      if (p[j0] == 0) break;                 // reached a free column
    }
    // augment along way[] chain (uniform serial walk, same-value LDS writes)
    int jj = j0;
    for (int guard = 0; guard < NN + 1 && jj != 0; ++guard) {
      int j1 = way[jj];
      int pj = (j1 == 0) ? i : p[j1];
      p[jj] = pj;
      jj = j1;
    }
  }
  __syncthreads();

  // loss: column j (0-idx) is matched to row r = p[j+1]-1; d = input[r] - target[j]
  int rA = p[c1A] - 1;
  int rB = p[c1B] - 1;
  float acc[ND];
  #pragma unroll
  for (int d = 0; d < ND; ++d) {
    float dA = inpS[rA * ND + d] - tA[d];
    float dB = inpS[rB * ND + d] - tB[d];
    if (d == 4) { dA = wrap_phi(dA); dB = wrap_phi(dB); }
    acc[d] = dA * dA + dB * dB;
  }
  #pragma unroll
  for (int d = 0; d < ND; ++d) {
    float s = acc[d];
    #pragma unroll
    for (int off = 32; off > 0; off >>= 1) s += __shfl_xor(s, off);
    if (lane == 0) atomicAdd(&sums[d], s);
  }
}

__global__ void set2set_finalize(const float* __restrict__ sums, float* __restrict__ out) {
  const float inv = 1.0f / (128.0f * 128.0f);
  float x  = sums[0] * inv;
  float y  = sums[1] * inv;
  float E  = sums[2] * inv;
  float th = sums[3] * inv;
  float ph = sums[4] * inv;
  out[1] = x; out[2] = y; out[3] = E; out[4] = th; out[5] = ph;
  out[0] = x + y + E + th + ph;
}

extern "C" void kernel_launch(void* const* d_in, const int* in_sizes, int n_in,
                              void* d_out, int out_size, void* d_ws, size_t ws_size,
                              hipStream_t stream) {
  const float* inp = (const float*)d_in[0];
  const float* tgt = (const float*)d_in[1];
  float* out  = (float*)d_out;
  float* sums = (float*)d_ws;

  hipMemsetAsync(sums, 0, ND * sizeof(float), stream);
  set2set_hungarian<<<dim3(NB), dim3(64), 0, stream>>>(inp, tgt, sums);
  set2set_finalize<<<dim3(1), dim3(1), 0, stream>>>(sums, out);
}

// Round 3
// 804.698 us; speedup vs baseline: 1.9128x; 1.9128x over previous
//
#include <hip/hip_runtime.h>

#define NN 128   // points per set
#define NB 128   // batches
#define ND 5     // feature dim
#define INFV 3.4028235e38f

__device__ __forceinline__ float wrap_phi(float x) {
  const float PI_F   = 3.14159265358979323846f;
  const float TWO_PI = 6.28318530717958647692f;
  float t = x + PI_F;
  float w = t - floorf(t * (1.0f / TWO_PI)) * TWO_PI;  // jnp.remainder semantics
  return w - PI_F;
}

// one DPP-permute + min step; masked-out lanes receive +INF (no-op under fmin)
#define DPP_MIN_STEP(x, ctrl, rmask)                                          \
  x = fminf(x, __int_as_float(__builtin_amdgcn_update_dpp(                    \
          0x7f800000, __float_as_int(x), (ctrl), (rmask), 0xF, false)))

__device__ __forceinline__ float wave_min_bcast(float x) {
  DPP_MIN_STEP(x, 0xB1,  0xF);  // quad_perm [1,0,3,2] : xor 1
  DPP_MIN_STEP(x, 0x4E,  0xF);  // quad_perm [2,3,0,1] : xor 2
  DPP_MIN_STEP(x, 0x141, 0xF);  // row_half_mirror     : combines 8-groups
  DPP_MIN_STEP(x, 0x140, 0xF);  // row_mirror          : combines 16-rows
  DPP_MIN_STEP(x, 0x142, 0xA);  // row_bcast15 -> rows 1,3 (lanes 16-31,48-63)
  DPP_MIN_STEP(x, 0x143, 0xC);  // row_bcast31 -> rows 2,3 (lane 63 = full min)
  return __int_as_float(__builtin_amdgcn_readlane(__float_as_int(x), 63));
}

__device__ __forceinline__ int rl_i(int v, int lane) {
  return __builtin_amdgcn_readlane(v, lane);
}
__device__ __forceinline__ float rl_f(float v, int lane) {
  return __int_as_float(__builtin_amdgcn_readlane(__float_as_int(v), lane));
}

// One block (64 threads = 1 wave) solves one batch's 128x128 assignment via
// Jonker-Volgenant. All solver state except the cost matrix lives in
// registers; cross-lane traffic is DPP / readlane / ballot (no LDS in the
// serial chain except the cost-row read).
__global__ __launch_bounds__(64) void set2set_hungarian(
    const float* __restrict__ inp, const float* __restrict__ tgt,
    float* __restrict__ sums)
{
  const int b = blockIdx.x;
  const int lane = threadIdx.x;

  __shared__ __align__(16) float Csh[NN * NN]; // cost matrix, row-major, 64 KB
  __shared__ float inpS[NN * ND];              // staged input rows

  const float* inB = inp + (size_t)b * NN * ND;
  const float* tgB = tgt + (size_t)b * NN * ND;

  for (int idx = lane; idx < NN * ND; idx += 64) inpS[idx] = inB[idx];
  __syncthreads();

  // this lane owns 0-indexed columns jA, jB  (1-indexed c1A, c1B)
  const int jA = 2 * lane;
  const int jB = 2 * lane + 1;
  const int c1A = jA + 1, c1B = jB + 1;

  float tA[ND], tB[ND];
  #pragma unroll
  for (int d = 0; d < ND; ++d) { tA[d] = tgB[jA * ND + d]; tB[d] = tgB[jB * ND + d]; }

  // build cost matrix: C[i][j] = ||input_i - target_j||_2
  #pragma unroll 4
  for (int i = 0; i < NN; ++i) {
    float sA = 0.f, sB = 0.f;
    #pragma unroll
    for (int d = 0; d < ND; ++d) {
      float x = inpS[i * ND + d];
      float da = x - tA[d]; sA = fmaf(da, da, sA);
      float db = x - tB[d]; sB = fmaf(db, db, sB);
    }
    ((float2*)(Csh + i * NN))[lane] = make_float2(sqrtf(sA), sqrtf(sB));
  }
  __syncthreads();

  // register-resident solver state (per lane, for its two columns)
  float vA = 0.f, vB = 0.f;   // column duals
  float uA = 0.f, uB = 0.f;   // dual of the ROW currently matched to col A/B
  int   pA = 0,   pB = 0;     // matched row (1-indexed), 0 = free
  int   wayA = 0, wayB = 0;

  for (int i = 1; i <= NN; ++i) {
    float mA = INFV, mB = INFV;
    bool usedA = false, usedB = false;
    float ucur = 0.0f;        // u[i] for the current augmenting row (uniform)
    int   j0 = 0, i0 = i;     // p[0] = i
    float ui0 = 0.0f;         // u[i0]
    int   jfree = 0;

    for (int guard = 0; guard <= NN + 1; ++guard) {
      usedA |= (j0 == c1A);
      usedB |= (j0 == c1B);
      const float2 c = ((const float2*)(Csh + (i0 - 1) * NN))[lane];
      if (!usedA) { float cur = c.x - ui0 - vA; if (cur < mA) { mA = cur; wayA = j0; } }
      if (!usedB) { float cur = c.y - ui0 - vB; if (cur < mB) { mB = cur; wayB = j0; } }

      // delta = exact min over unused columns (DPP reduce, no LDS)
      float x = fminf(usedA ? INFV : mA, usedB ? INFV : mB);
      float delta = wave_min_bcast(x);

      // argmin column, lowest-index tie-break (matches np.argmin); BEFORE -= delta
      unsigned long long mskA = __ballot(!usedA && (mA == delta));
      unsigned long long mskB = __ballot(!usedB && (mB == delta));
      unsigned long long msk  = mskA | mskB;
      int l  = __ffsll(msk) - 1;
      int j1 = 2 * l + 1 + (((mskA >> l) & 1ull) ? 0 : 1);

      // dual updates (registers only)
      ucur += delta;
      if (usedA) { vA -= delta; uA += delta; } else { mA -= delta; }
      if (usedB) { vB -= delta; uB += delta; } else { mB -= delta; }

      // p[j1], u[p[j1]] via uniform readlane
      int owner = (j1 - 1) >> 1, slot = (j1 - 1) & 1;
      int plo = rl_i(pA, owner), phi = rl_i(pB, owner);
      int pj1 = slot ? phi : plo;
      if (pj1 == 0) { jfree = j1; break; }
      float ulo = rl_f(uA, owner), uhi = rl_f(uB, owner);
      ui0 = slot ? uhi : ulo;
      j0 = j1; i0 = pj1;
    }

    // augment along way[] chain; transfer row + its dual between columns
    int jj = jfree;
    for (int g = 0; g < NN + 1 && jj != 0; ++g) {
      int owner = (jj - 1) >> 1, slot = (jj - 1) & 1;
      int wlo = rl_i(wayA, owner), whi = rl_i(wayB, owner);
      int wj = slot ? whi : wlo;
      int pnew; float unew;
      if (wj == 0) { pnew = i; unew = ucur; }
      else {
        int o2 = (wj - 1) >> 1, s2 = (wj - 1) & 1;
        int plo2 = rl_i(pA, o2), phi2 = rl_i(pB, o2);
        pnew = s2 ? phi2 : plo2;
        float ulo2 = rl_f(uA, o2), uhi2 = rl_f(uB, o2);
        unew = s2 ? uhi2 : ulo2;
      }
      if (lane == owner) {
        if (slot) { pB = pnew; uB = unew; } else { pA = pnew; uA = unew; }
      }
      jj = wj;
    }
  }

  // loss: column j (0-idx) is matched to row r = p-1; d = input[r] - target[j]
  int rA = pA - 1;
  int rB = pB - 1;
  float acc[ND];
  #pragma unroll
  for (int d = 0; d < ND; ++d) {
    float dA = inpS[rA * ND + d] - tA[d];
    float dB = inpS[rB * ND + d] - tB[d];
    if (d == 4) { dA = wrap_phi(dA); dB = wrap_phi(dB); }
    acc[d] = dA * dA + dB * dB;
  }
  #pragma unroll
  for (int d = 0; d < ND; ++d) {
    float s = acc[d];
    #pragma unroll
    for (int off = 32; off > 0; off >>= 1) s += __shfl_xor(s, off);
    if (lane == 0) atomicAdd(&sums[d], s);
  }
}

__global__ void set2set_finalize(const float* __restrict__ sums, float* __restrict__ out) {
  const float inv = 1.0f / (128.0f * 128.0f);
  float x  = sums[0] * inv;
  float y  = sums[1] * inv;
  float E  = sums[2] * inv;
  float th = sums[3] * inv;
  float ph = sums[4] * inv;
  out[1] = x; out[2] = y; out[3] = E; out[4] = th; out[5] = ph;
  out[0] = x + y + E + th + ph;
}

extern "C" void kernel_launch(void* const* d_in, const int* in_sizes, int n_in,
                              void* d_out, int out_size, void* d_ws, size_t ws_size,
                              hipStream_t stream) {
  const float* inp = (const float*)d_in[0];
  const float* tgt = (const float*)d_in[1];
  float* out  = (float*)d_out;
  float* sums = (float*)d_ws;

  hipMemsetAsync(sums, 0, ND * sizeof(float), stream);
  set2set_hungarian<<<dim3(NB), dim3(64), 0, stream>>>(inp, tgt, sums);
  set2set_finalize<<<dim3(1), dim3(1), 0, stream>>>(sums, out);
}

// Round 4
// 533.801 us; speedup vs baseline: 2.8835x; 1.5075x over previous
//
#include <hip/hip_runtime.h>

#define NN 128   // points per set
#define NB 128   // batches
#define ND 5     // feature dim
#define INFV 3.4028235e38f

__device__ __forceinline__ float wrap_phi(float x) {
  const float PI_F   = 3.14159265358979323846f;
  const float TWO_PI = 6.28318530717958647692f;
  float t = x + PI_F;
  float w = t - floorf(t * (1.0f / TWO_PI)) * TWO_PI;  // jnp.remainder semantics
  return w - PI_F;
}

// one DPP-permute + min step; masked-out lanes receive +INF (no-op under fmin)
#define DPP_MIN_STEP(x, ctrl, rmask)                                          \
  x = fminf(x, __int_as_float(__builtin_amdgcn_update_dpp(                    \
          0x7f800000, __float_as_int(x), (ctrl), (rmask), 0xF, false)))

__device__ __forceinline__ float wave_min_bcast(float x) {
  DPP_MIN_STEP(x, 0xB1,  0xF);  // quad_perm xor 1
  DPP_MIN_STEP(x, 0x4E,  0xF);  // quad_perm xor 2
  DPP_MIN_STEP(x, 0x141, 0xF);  // row_half_mirror
  DPP_MIN_STEP(x, 0x140, 0xF);  // row_mirror
  DPP_MIN_STEP(x, 0x142, 0xA);  // row_bcast15
  DPP_MIN_STEP(x, 0x143, 0xC);  // row_bcast31 (lane 63 = full min)
  return __int_as_float(__builtin_amdgcn_readlane(__float_as_int(x), 63));
}

__device__ __forceinline__ int rl_i(int v, int lane) {
  return __builtin_amdgcn_readlane(v, lane);
}
__device__ __forceinline__ float rl_f(float v, int lane) {
  return __int_as_float(__builtin_amdgcn_readlane(__float_as_int(v), lane));
}

// One block (64 threads = 1 wave) solves one batch's 128x128 assignment via
// Jonker-Volgenant with LAPJV column-reduction initialization. Solver state
// (duals, matching, way) is register-resident; cross-lane via DPP/readlane/
// ballot. LDS holds only the cost matrix + staging.
__global__ __launch_bounds__(64) void set2set_hungarian(
    const float* __restrict__ inp, const float* __restrict__ tgt,
    float* __restrict__ sums)
{
  const int b = blockIdx.x;
  const int lane = threadIdx.x;

  __shared__ __align__(16) float Csh[NN * NN]; // cost matrix, row-major, 64 KB
  __shared__ float inpS[NN * ND];              // staged input rows
  __shared__ int   rowOwner[NN + 1];           // arbitration: winning column per row

  const float* inB = inp + (size_t)b * NN * ND;
  const float* tgB = tgt + (size_t)b * NN * ND;

  for (int idx = lane; idx < NN * ND; idx += 64) inpS[idx] = inB[idx];
  for (int idx = lane; idx <= NN; idx += 64) rowOwner[idx] = 0x7fffffff;
  __syncthreads();

  // this lane owns 0-indexed columns jA, jB  (1-indexed c1A, c1B)
  const int jA = 2 * lane;
  const int jB = 2 * lane + 1;
  const int c1A = jA + 1, c1B = jB + 1;

  float tA[ND], tB[ND];
  #pragma unroll
  for (int d = 0; d < ND; ++d) { tA[d] = tgB[jA * ND + d]; tB[d] = tgB[jB * ND + d]; }

  // build cost matrix: C[i][j] = ||input_i - target_j||_2
  #pragma unroll 4
  for (int i = 0; i < NN; ++i) {
    float sA = 0.f, sB = 0.f;
    #pragma unroll
    for (int d = 0; d < ND; ++d) {
      float x = inpS[i * ND + d];
      float da = x - tA[d]; sA = fmaf(da, da, sA);
      float db = x - tB[d]; sB = fmaf(db, db, sB);
    }
    ((float2*)(Csh + i * NN))[lane] = make_float2(sqrtf(sA), sqrtf(sB));
  }
  __syncthreads();

  // ---- LAPJV column reduction ----
  // v[j] = min_i C[i][j]; greedily match each column's argmin row (lowest
  // column index wins a contested row). u[i] = 0. Reduced costs >= 0 and
  // matched pairs have reduced cost 0 -> dual-feasible partial matching.
  float vA = INFV, vB = INFV;  // column duals
  int   rmA = 1,  rmB = 1;     // argmin row (1-indexed, first occurrence)
  for (int i = 0; i < NN; ++i) {
    float2 c = ((const float2*)(Csh + i * NN))[lane];
    if (c.x < vA) { vA = c.x; rmA = i + 1; }
    if (c.y < vB) { vB = c.y; rmB = i + 1; }
  }
  atomicMin(&rowOwner[rmA], c1A);
  atomicMin(&rowOwner[rmB], c1B);
  __syncthreads();

  int   pA = (rowOwner[rmA] == c1A) ? rmA : 0;  // matched row per column, 0 = free
  int   pB = (rowOwner[rmB] == c1B) ? rmB : 0;
  float uA = 0.f, uB = 0.f;   // dual of the row matched to col A/B
  int   wayA = 0, wayB = 0;

  // free-row bitmask (rows nobody claimed), wave-uniform in SGPRs
  unsigned long long freeLo = __ballot(rowOwner[1 + lane]  == 0x7fffffff);
  unsigned long long freeHi = __ballot(rowOwner[65 + lane] == 0x7fffffff);

  // ---- augmenting search (Dijkstra) for each remaining free row ----
  for (int i = 1; i <= NN; ++i) {
    unsigned long long fb = (i <= 64) ? (freeLo >> (i - 1)) : (freeHi >> (i - 65));
    if (!(fb & 1ull)) continue;

    float mA = INFV, mB = INFV;
    bool usedA = false, usedB = false;
    float ucur = 0.0f;        // u[i] for the current augmenting row (uniform)
    int   j0 = 0, i0 = i;     // p[0] = i
    float ui0 = 0.0f;         // u[i0]
    int   jfree = 0;

    for (int guard = 0; guard <= NN + 1; ++guard) {
      usedA |= (j0 == c1A);
      usedB |= (j0 == c1B);
      const float2 c = ((const float2*)(Csh + (i0 - 1) * NN))[lane];
      if (!usedA) { float cur = c.x - ui0 - vA; if (cur < mA) { mA = cur; wayA = j0; } }
      if (!usedB) { float cur = c.y - ui0 - vB; if (cur < mB) { mB = cur; wayB = j0; } }

      // delta = exact min over unused columns (DPP reduce, no LDS)
      float x = fminf(usedA ? INFV : mA, usedB ? INFV : mB);
      float delta = wave_min_bcast(x);

      // argmin column, lowest-index tie-break; evaluated BEFORE -= delta
      unsigned long long mskA = __ballot(!usedA && (mA == delta));
      unsigned long long mskB = __ballot(!usedB && (mB == delta));
      unsigned long long msk  = mskA | mskB;
      int l  = __ffsll(msk) - 1;
      int j1 = 2 * l + 1 + (((mskA >> l) & 1ull) ? 0 : 1);

      // dual updates (registers only)
      ucur += delta;
      if (usedA) { vA -= delta; uA += delta; } else { mA -= delta; }
      if (usedB) { vB -= delta; uB += delta; } else { mB -= delta; }

      // p[j1], u[p[j1]] via uniform readlane
      int owner = (j1 - 1) >> 1, slot = (j1 - 1) & 1;
      int plo = rl_i(pA, owner), phi = rl_i(pB, owner);
      int pj1 = slot ? phi : plo;
      if (pj1 == 0) { jfree = j1; break; }
      float ulo = rl_f(uA, owner), uhi = rl_f(uB, owner);
      ui0 = slot ? uhi : ulo;
      j0 = j1; i0 = pj1;
    }

    // augment along way[] chain; transfer row + its dual between columns
    int jj = jfree;
    for (int g = 0; g < NN + 1 && jj != 0; ++g) {
      int owner = (jj - 1) >> 1, slot = (jj - 1) & 1;
      int wlo = rl_i(wayA, owner), whi = rl_i(wayB, owner);
      int wj = slot ? whi : wlo;
      int pnew; float unew;
      if (wj == 0) { pnew = i; unew = ucur; }
      else {
        int o2 = (wj - 1) >> 1, s2 = (wj - 1) & 1;
        int plo2 = rl_i(pA, o2), phi2 = rl_i(pB, o2);
        pnew = s2 ? phi2 : plo2;
        float ulo2 = rl_f(uA, o2), uhi2 = rl_f(uB, o2);
        unew = s2 ? uhi2 : ulo2;
      }
      if (lane == owner) {
        if (slot) { pB = pnew; uB = unew; } else { pA = pnew; uA = unew; }
      }
      jj = wj;
    }
  }

  // loss: column j (0-idx) is matched to row r = p-1; d = input[r] - target[j]
  int rA = pA - 1;
  int rB = pB - 1;
  float acc[ND];
  #pragma unroll
  for (int d = 0; d < ND; ++d) {
    float dA = inpS[rA * ND + d] - tA[d];
    float dB = inpS[rB * ND + d] - tB[d];
    if (d == 4) { dA = wrap_phi(dA); dB = wrap_phi(dB); }
    acc[d] = dA * dA + dB * dB;
  }
  #pragma unroll
  for (int d = 0; d < ND; ++d) {
    float s = acc[d];
    #pragma unroll
    for (int off = 32; off > 0; off >>= 1) s += __shfl_xor(s, off);
    if (lane == 0) atomicAdd(&sums[d], s);
  }
}

__global__ void set2set_finalize(const float* __restrict__ sums, float* __restrict__ out) {
  const float inv = 1.0f / (128.0f * 128.0f);
  float x  = sums[0] * inv;
  float y  = sums[1] * inv;
  float E  = sums[2] * inv;
  float th = sums[3] * inv;
  float ph = sums[4] * inv;
  out[1] = x; out[2] = y; out[3] = E; out[4] = th; out[5] = ph;
  out[0] = x + y + E + th + ph;
}

extern "C" void kernel_launch(void* const* d_in, const int* in_sizes, int n_in,
                              void* d_out, int out_size, void* d_ws, size_t ws_size,
                              hipStream_t stream) {
  const float* inp = (const float*)d_in[0];
  const float* tgt = (const float*)d_in[1];
  float* out  = (float*)d_out;
  float* sums = (float*)d_ws;

  hipMemsetAsync(sums, 0, ND * sizeof(float), stream);
  set2set_hungarian<<<dim3(NB), dim3(64), 0, stream>>>(inp, tgt, sums);
  set2set_finalize<<<dim3(1), dim3(1), 0, stream>>>(sums, out);
}